// Round 1
// baseline (20405.762 us; speedup 1.0000x reference)
//
#include <hip/hip_runtime.h>

#define BLOCK 256

// sigmoid(x) = 1/(1+e^-x); fast native exp + fast divide (rel err ~1e-6, fine vs 9e-3 tol)
__device__ __forceinline__ float sigm(float x) {
    return __fdividef(1.0f, 1.0f + __expf(-x));
}
// tanh(x) = 1 - 2/(e^{2x}+1); saturates correctly at +/-inf via inf/0 of __expf
__device__ __forceinline__ float tanhfast(float x) {
    return 1.0f - 2.0f * __fdividef(1.0f, 1.0f + __expf(2.0f * x));
}

// One 8-step LSTM (input dim 1, H=64), PyTorch gate order i,f,g,o.
// h_old lives in LDS at hl[k*BLOCK + tid] (lane-consecutive -> conflict-free).
// c[] and hn[] are register arrays (all indexing constant after unroll).
__device__ __forceinline__ void lstm_seq(
    const float xs[8],
    const float* __restrict__ Wih, const float* __restrict__ Whh,
    const float* __restrict__ bih, const float* __restrict__ bhh,
    float* __restrict__ hl, int tid,
    float* __restrict__ c, float* __restrict__ hn)
{
    // ---- t = 0 peeled: h = 0, c = 0 -> gates = x*Wih + b only (skips the 64x256 matvec)
    {
        const float xt = xs[0];
        #pragma unroll
        for (int j = 0; j < 64; ++j) {
            float ai = xt * Wih[j]       + bih[j]       + bhh[j];
            float af = xt * Wih[64 + j]  + bih[64 + j]  + bhh[64 + j];  // unused vs c=0 but cheap
            float ag = xt * Wih[128 + j] + bih[128 + j] + bhh[128 + j];
            float ao = xt * Wih[192 + j] + bih[192 + j] + bhh[192 + j];
            (void)af;
            float cn = sigm(ai) * tanhfast(ag);   // f*0 + i*g
            c[j] = cn;
            float hv = sigm(ao) * tanhfast(cn);
            hn[j] = hv;
            hl[j * BLOCK + tid] = hv;
        }
    }

    #pragma unroll 1
    for (int t = 1; t < 8; ++t) {
        const float xt = xs[t];
        // j in groups of 4: 16 accumulators -> 16 FMAs per LDS read of h[k]
        #pragma unroll
        for (int jg = 0; jg < 16; ++jg) {
            float acc[4][4];
            #pragma unroll
            for (int g = 0; g < 4; ++g)
                #pragma unroll
                for (int u = 0; u < 4; ++u) {
                    int row = g * 64 + jg * 4 + u;
                    acc[g][u] = xt * Wih[row] + bih[row] + bhh[row];
                }
            #pragma unroll 4
            for (int k = 0; k < 64; ++k) {
                float hk = hl[k * BLOCK + tid];
                #pragma unroll
                for (int g = 0; g < 4; ++g)
                    #pragma unroll
                    for (int u = 0; u < 4; ++u)
                        acc[g][u] += hk * Whh[(g * 64 + jg * 4 + u) * 64 + k];  // wave-uniform -> s_load
            }
            #pragma unroll
            for (int u = 0; u < 4; ++u) {
                int j = jg * 4 + u;
                float cn = sigm(acc[1][u]) * c[j] + sigm(acc[0][u]) * tanhfast(acc[2][u]);
                c[j] = cn;
                hn[j] = sigm(acc[3][u]) * tanhfast(cn);
            }
        }
        // commit h_new -> LDS for next step (each thread owns its column: no barrier needed)
        if (t < 7) {
            #pragma unroll
            for (int j = 0; j < 64; ++j) hl[j * BLOCK + tid] = hn[j];
        }
    }
}

extern "C" __global__ void __launch_bounds__(BLOCK, 2) lstm_fused(
    const float* __restrict__ inputs,
    const float* __restrict__ Wih1, const float* __restrict__ Whh1,
    const float* __restrict__ bih1, const float* __restrict__ bhh1,
    const float* __restrict__ Wih2, const float* __restrict__ Whh2,
    const float* __restrict__ bih2, const float* __restrict__ bhh2,
    const float* __restrict__ mW0, const float* __restrict__ mb0,
    const float* __restrict__ mW1, const float* __restrict__ mb1,
    const float* __restrict__ mW2, const float* __restrict__ mb2,
    const float* __restrict__ pW, const float* __restrict__ pb,
    float* __restrict__ out, int n)
{
    __shared__ float hl[64 * BLOCK];   // 64 KB -> 2 blocks/CU
    const int tid = threadIdx.x;
    const int b = blockIdx.x * BLOCK + tid;
    if (b >= n) return;
    const float* xin = inputs + (size_t)b * 18;

    float out0 = pb[0], out1 = pb[1];

    // ---- MLP branch on feat = x[16:18]; folds hid2 directly into out via pW[:,256:288]
    {
        float f0 = xin[16], f1 = xin[17];
        float hid0[64];
        #pragma unroll
        for (int i = 0; i < 64; ++i) {
            float v = mW0[2 * i] * f0 + mW0[2 * i + 1] * f1 + mb0[i];
            hid0[i] = fmaxf(v, 0.0f);
        }
        #pragma unroll 1
        for (int i = 0; i < 64; ++i) {         // hid1 -> LDS (reused later by LSTM h)
            float a = mb1[i];
            #pragma unroll
            for (int k = 0; k < 64; ++k) a += mW1[i * 64 + k] * hid0[k];
            hl[i * BLOCK + tid] = fmaxf(a, 0.0f);
        }
        #pragma unroll 1
        for (int i = 0; i < 32; ++i) {
            float a = mb2[i];
            #pragma unroll 8
            for (int k = 0; k < 64; ++k) a += mW2[i * 64 + k] * hl[k * BLOCK + tid];
            out0 += pW[256 + i] * a;
            out1 += pW[288 + 256 + i] * a;
        }
    }

    float xs[8], c[64], hn[64];

    // ---- LSTM1 on x[0:8]; z columns: h1 -> 0..63, c1 -> 64..127
    #pragma unroll
    for (int t = 0; t < 8; ++t) xs[t] = xin[t];
    lstm_seq(xs, Wih1, Whh1, bih1, bhh1, hl, tid, c, hn);
    #pragma unroll
    for (int j = 0; j < 64; ++j) {
        out0 += pW[j] * hn[j]        + pW[64 + j] * c[j];
        out1 += pW[288 + j] * hn[j]  + pW[288 + 64 + j] * c[j];
    }

    // ---- LSTM2 on x[8:16]; z columns: h2 -> 128..191, c2 -> 192..255
    #pragma unroll
    for (int t = 0; t < 8; ++t) xs[t] = xin[8 + t];
    lstm_seq(xs, Wih2, Whh2, bih2, bhh2, hl, tid, c, hn);
    #pragma unroll
    for (int j = 0; j < 64; ++j) {
        out0 += pW[128 + j] * hn[j]       + pW[192 + j] * c[j];
        out1 += pW[288 + 128 + j] * hn[j] + pW[288 + 192 + j] * c[j];
    }

    out[(size_t)b * 2]     = out0;
    out[(size_t)b * 2 + 1] = out1;
}

extern "C" void kernel_launch(void* const* d_in, const int* in_sizes, int n_in,
                              void* d_out, int out_size, void* d_ws, size_t ws_size,
                              hipStream_t stream) {
    const int n = in_sizes[0] / 18;           // batch count (1048576)
    const int grid = (n + BLOCK - 1) / BLOCK;
    lstm_fused<<<grid, BLOCK, 0, stream>>>(
        (const float*)d_in[0],
        (const float*)d_in[1], (const float*)d_in[2],
        (const float*)d_in[3], (const float*)d_in[4],
        (const float*)d_in[5], (const float*)d_in[6],
        (const float*)d_in[7], (const float*)d_in[8],
        (const float*)d_in[9], (const float*)d_in[10],
        (const float*)d_in[11], (const float*)d_in[12],
        (const float*)d_in[13], (const float*)d_in[14],
        (const float*)d_in[15], (const float*)d_in[16],
        (float*)d_out, n);
}